// Round 14
// baseline (497.775 us; speedup 1.0000x reference)
//
#include <hip/hip_runtime.h>
#include <math.h>

#define NTX_EPS 1e-8f

typedef __fp16 half8 __attribute__((ext_vector_type(8)));
typedef __fp16 half2v __attribute__((ext_vector_type(2)));
typedef float f32x4 __attribute__((ext_vector_type(4)));

union H8 { half8 v8; half2v v2[4]; };

__device__ __forceinline__ half8 pack8(const float4& a, const float4& b) {
    H8 u;
    u.v2[0] = __builtin_amdgcn_cvt_pkrtz(a.x, a.y);
    u.v2[1] = __builtin_amdgcn_cvt_pkrtz(a.z, a.w);
    u.v2[2] = __builtin_amdgcn_cvt_pkrtz(b.x, b.y);
    u.v2[3] = __builtin_amdgcn_cvt_pkrtz(b.z, b.w);
    return u.v8;
}

// Opaque async load (R12-proven): one global_load_dwordx4 per call, compiler
// cannot recycle the destinations into a serialized chain.
__device__ __forceinline__ float4 gl4(const float* p) {
    float4 d;
    asm volatile("global_load_dwordx4 %0, %1, off" : "=v"(d) : "v"(p) : "memory");
    return d;
}
#define WAITVM(n) do { asm volatile("s_waitcnt vmcnt(" #n ")" ::: "memory"); \
                       __builtin_amdgcn_sched_barrier(0); } while (0)

#define ISSUE(g, s) \
    float4 g##T0 = gl4(tsrc + (s) * 32); \
    float4 g##T1 = gl4(tsrc + (s) * 32 + 4); \
    float4 g##R0 = gl4(rsrc + (s) * 32); \
    float4 g##R1 = gl4(rsrc + (s) * 32 + 4);

#define COMPUTE(g) { \
    half8 tf = pack8(g##T0, g##T1); \
    half8 rf = pack8(g##R0, g##R1); \
    acc_tt = __builtin_amdgcn_mfma_f32_16x16x32_f16(tf, tf, acc_tt, 0, 0, 0); \
    acc_tr = __builtin_amdgcn_mfma_f32_16x16x32_f16(tf, rf, acc_tr, 0, 0, 0); \
    acc_rr = __builtin_amdgcn_mfma_f32_16x16x32_f16(rf, rf, acc_rr, 0, 0, 0); }

// ws layout (floats):
//   [ (b*6+slot)*528 ]        : Gram partials, slots 0..5
//   [ LOSS_OFF + b*3 + lvl ]  : per-(batch,level) losses (768)
//   ints at CNT region        : 512 arrival counters + 1 done counter
#define LOSS_OFF (256 * 6 * 528)
#define NB 256

// Single fused kernel: 1792 blocks x 256 threads (4 waves). Block = (b, slot);
// wave w owns d-quarter w*256 (8 K-steps of 32). Verified MFMA Gram (R7/R12):
// lane l feeds row l&15, k-group l>>4; one half8 is both A and B operand;
// mfma(t,t)/(t,r)/(r,r); C/D col=l&15, row=kg*4+r. ISA load ring: 16-20
// dwordx4 outstanding, counted vmcnt.
// R14: K2/K3 fused in via threadfence-reduction (last-arrival finishes its
// (b,lvl); 768th loss-writer sums all losses -> out). Removes ~8-12us of
// launch/dispatch tail that R13 identified as the wall-vs-profile gap.
// Deterministic: finisher identity varies, but all sums use fixed loop order.
__global__ __launch_bounds__(256, 2)
void ntxent_fused(const float* __restrict__ ts0, const float* __restrict__ rs0,
                  const float* __restrict__ ts1, const float* __restrict__ rs1,
                  const float* __restrict__ ts2, const float* __restrict__ rs2,
                  float* __restrict__ ws, int* __restrict__ cnt,
                  int* __restrict__ done, float* __restrict__ out)
{
    __shared__ float redTT[4][256];
    __shared__ float redTR[4][256];
    __shared__ float redRR[4][16];
    __shared__ float Gs[16][33];
    __shared__ float rn2[16], tnS[16], rnS[16];
    __shared__ float partial[4];
    __shared__ int lastFlag;

    const int bid  = blockIdx.x;
    const int b    = bid / 7;
    const int slot = bid % 7;

    const float* tp; const float* rp; int D; int chunk0;
    if (slot < 4)      { tp = ts0; rp = rs0; D = 4096; chunk0 = slot; }
    else if (slot < 6) { tp = ts1; rp = rs1; D = 2048; chunk0 = slot - 4; }
    else               { tp = ts2; rp = rs2; D = 1024; chunk0 = 0; }

    const int t   = threadIdx.x;
    const int w   = t >> 6;
    const int l   = t & 63;
    const int row = l & 15;
    const int kg  = l >> 4;

    const size_t base = (size_t)b * 16 * D + (size_t)row * D
                      + (size_t)chunk0 * 1024 + (size_t)w * 256 + (size_t)kg * 8;
    const float* tsrc = tp + base;
    const float* rsrc = rp + base;

    f32x4 acc_tt = {0.f, 0.f, 0.f, 0.f};
    f32x4 acc_tr = {0.f, 0.f, 0.f, 0.f};
    f32x4 acc_rr = {0.f, 0.f, 0.f, 0.f};

    // ---- load ring: 8 K-steps, 4 loads each; 16-20 outstanding ----
    ISSUE(g0, 0) ISSUE(g1, 1) ISSUE(g2, 2) ISSUE(g3, 3)
    ISSUE(g4, 4) WAITVM(16); COMPUTE(g0)
    ISSUE(g5, 5) WAITVM(16); COMPUTE(g1)
    ISSUE(g6, 6) WAITVM(16); COMPUTE(g2)
    ISSUE(g7, 7) WAITVM(16); COMPUTE(g3)
    WAITVM(12);  COMPUTE(g4)
    WAITVM(8);   COMPUTE(g5)
    WAITVM(4);   COMPUTE(g6)
    WAITVM(0);   COMPUTE(g7)

    // ---- combine 4 wave partials via LDS ----
    const int m = row;
#pragma unroll
    for (int r = 0; r < 4; ++r) {
        const int n = kg * 4 + r;
        redTT[w][n * 16 + m] = acc_tt[r];
        redTR[w][n * 16 + m] = acc_tr[r];
    }
    if ((m >> 2) == kg) redRR[w][m] = acc_rr[m & 3];
    __syncthreads();

    const int n  = t >> 4;
    const int mm = t & 15;
    const float tt = redTT[0][t] + redTT[1][t] + redTT[2][t] + redTT[3][t];
    const float tr = redTR[0][t] + redTR[1][t] + redTR[2][t] + redTR[3][t];

    int lvlIdx;
    if (slot == 6) {
        // level 2: Gram complete in-block
        Gs[n][mm]      = tt;
        Gs[n][16 + mm] = tr;
        if (t < 16)
            rn2[t] = redRR[0][t] + redRR[1][t] + redRR[2][t] + redRR[3][t];
        __syncthreads();
        lvlIdx = 2;
    } else {
        // write partials, then last-arrival finishes this (b,lvl)
        float* slotp = ws + (size_t)(b * 6 + slot) * 528;
        slotp[n * 32 + mm]      = tt;
        slotp[n * 32 + 16 + mm] = tr;
        if (t < 16)
            slotp[512 + t] = redRR[0][t] + redRR[1][t] + redRR[2][t] + redRR[3][t];
        __threadfence();                    // release partials
        __syncthreads();
        const int lvl  = (slot < 4) ? 0 : 1;
        const int need = (slot < 4) ? 4 : 2;
        if (t == 0)
            lastFlag = (atomicAdd(&cnt[b * 2 + lvl], 1) == need - 1);
        __syncthreads();
        if (!lastFlag) return;
        __threadfence();                    // acquire others' partials
        const int gbase = b * 6 + (lvl ? 4 : 0);
        for (int e = t; e < 512; e += 256) {
            float s = 0.f;
            for (int c = 0; c < need; ++c)
                s += ws[(size_t)(gbase + c) * 528 + e];
            Gs[e >> 5][e & 31] = s;
        }
        if (t < 16) {
            float s = 0.f;
            for (int c = 0; c < need; ++c)
                s += ws[(size_t)(gbase + c) * 528 + 512 + t];
            rn2[t] = s;
        }
        __syncthreads();
        lvlIdx = lvl;
    }

    // ---- loss for this (b, lvlIdx) ----
    if (t < 16) {
        tnS[t] = fmaxf(sqrtf(Gs[t][t]), NTX_EPS);
        rnS[t] = fmaxf(sqrtf(rn2[t]), NTX_EPS);
    }
    __syncthreads();

    float loss = 0.f;
    if (t < 16) {
        const int nn = t;
        const float itn = 2.0f / tnS[nn];        // includes 1/temperature
        float lg[32];
#pragma unroll
        for (int j = 0; j < 16; ++j)
            lg[j] = Gs[nn][16 + j] * itn / rnS[j];     // s_tr row
#pragma unroll
        for (int k = 0; k < 16; ++k)
            lg[16 + k] = Gs[nn][k] * itn / tnS[k];     // s_tt row
        const float pos = lg[nn];
        float mx = -3.4e38f;
#pragma unroll
        for (int j = 0; j < 32; ++j)
            mx = (j == 16 + nn) ? mx : fmaxf(mx, lg[j]);   // exclude tt diag
        float sm = 0.f;
#pragma unroll
        for (int j = 0; j < 32; ++j)
            sm += (j == 16 + nn) ? 0.f : expf(lg[j] - mx);
        loss = logf(sm) + mx - pos;
    }
    loss += __shfl_xor(loss, 1, 64);
    loss += __shfl_xor(loss, 2, 64);
    loss += __shfl_xor(loss, 4, 64);
    loss += __shfl_xor(loss, 8, 64);
    if (t == 0) ws[LOSS_OFF + b * 3 + lvlIdx] = loss;

    // ---- completion: 768th loss-writer sums all losses -> out ----
    __threadfence();                        // release the loss cell
    __syncthreads();
    if (t == 0)
        lastFlag = (atomicAdd(done, 1) == 3 * NB - 1);
    __syncthreads();
    if (!lastFlag) return;
    __threadfence();                        // acquire all loss cells

    float s = 0.f;
    for (int i = t; i < 3 * NB; i += 256) s += ws[LOSS_OFF + i];
    s += __shfl_xor(s, 1, 64);
    s += __shfl_xor(s, 2, 64);
    s += __shfl_xor(s, 4, 64);
    s += __shfl_xor(s, 8, 64);
    s += __shfl_xor(s, 16, 64);
    s += __shfl_xor(s, 32, 64);
    if (l == 0) partial[w] = s;
    __syncthreads();
    if (t == 0)
        out[0] = (partial[0] + partial[1] + partial[2] + partial[3])
                 * (1.0f / 512.0f);
}

extern "C" void kernel_launch(void* const* d_in, const int* in_sizes, int n_in,
                              void* d_out, int out_size, void* d_ws, size_t ws_size,
                              hipStream_t stream) {
    const float* ts0 = (const float*)d_in[0];
    const float* rs0 = (const float*)d_in[1];
    const float* ts1 = (const float*)d_in[2];
    const float* rs1 = (const float*)d_in[3];
    const float* ts2 = (const float*)d_in[4];
    const float* rs2 = (const float*)d_in[5];
    float* out = (float*)d_out;
    float* ws  = (float*)d_ws;

    // counters live after the loss cells; zero them every call (graph-safe)
    int* cnt  = (int*)(ws + LOSS_OFF + 3 * NB);
    int* done = cnt + 2 * NB;
    hipMemsetAsync(cnt, 0, (2 * NB + 1) * sizeof(int), stream);

    const int B = in_sizes[0] / (16 * 4096);   // 256
    hipLaunchKernelGGL(ntxent_fused, dim3(B * 7), dim3(256), 0, stream,
                       ts0, rs0, ts1, rs1, ts2, rs2, ws, cnt, done, out);
}

// Round 15
// 58.998 us; speedup vs baseline: 8.4372x; 8.4372x over previous
//
#include <hip/hip_runtime.h>
#include <math.h>

#define NTX_EPS 1e-8f

typedef __fp16 half8 __attribute__((ext_vector_type(8)));
typedef __fp16 half2v __attribute__((ext_vector_type(2)));
typedef float f32x4 __attribute__((ext_vector_type(4)));

union H8 { half8 v8; half2v v2[4]; };

__device__ __forceinline__ half8 pack8(const float4& a, const float4& b) {
    H8 u;
    u.v2[0] = __builtin_amdgcn_cvt_pkrtz(a.x, a.y);
    u.v2[1] = __builtin_amdgcn_cvt_pkrtz(a.z, a.w);
    u.v2[2] = __builtin_amdgcn_cvt_pkrtz(b.x, b.y);
    u.v2[3] = __builtin_amdgcn_cvt_pkrtz(b.z, b.w);
    return u.v8;
}

// Opaque async load (R12-proven): one global_load_dwordx4 per call; compiler
// cannot recycle destinations into a serialized chain.
__device__ __forceinline__ float4 gl4(const float* p) {
    float4 d;
    asm volatile("global_load_dwordx4 %0, %1, off" : "=v"(d) : "v"(p) : "memory");
    return d;
}
#define WAITVM(n) do { asm volatile("s_waitcnt vmcnt(" #n ")" ::: "memory"); \
                       __builtin_amdgcn_sched_barrier(0); } while (0)

#define ISSUE(g, s) \
    float4 g##T0 = gl4(tsrc + (s) * 32); \
    float4 g##T1 = gl4(tsrc + (s) * 32 + 4); \
    float4 g##R0 = gl4(rsrc + (s) * 32); \
    float4 g##R1 = gl4(rsrc + (s) * 32 + 4);

#define COMPUTE(g) { \
    half8 tf = pack8(g##T0, g##T1); \
    half8 rf = pack8(g##R0, g##R1); \
    acc_tt = __builtin_amdgcn_mfma_f32_16x16x32_f16(tf, tf, acc_tt, 0, 0, 0); \
    acc_tr = __builtin_amdgcn_mfma_f32_16x16x32_f16(tf, rf, acc_tr, 0, 0, 0); \
    acc_rr = __builtin_amdgcn_mfma_f32_16x16x32_f16(rf, rf, acc_rr, 0, 0, 0); }

// SINGLE kernel: 768 blocks x 1024 threads (16 waves). Block = (b, lvl)
// (lvl = bid%3 so adjacent blocks mix levels on a CU). Each wave runs the
// verified R12 ISA load-ring on its own d-sub-range: lvl0 8 K-steps/wave,
// lvl1 4, lvl2 2 (K-step = 32 floats; lane l feeds Gram row l&15, k-group
// l>>4; one half8 serves as both A and B; mfma(t,t)/(t,r)/(r,r); C/D layout
// col=l&15, row=kg*4+r). One in-block LDS reduce over 16 wave partials,
// loss in-block, one atomicAdd per block.
// R14 lesson: NO device-scope fences (threadfence storm -> 8x regression);
// cross-block reduction eliminated structurally instead (whole level fits
// one block). Kills K2+K3+two launch gaps (~10us of R12's 60.3 wall) and
// all ws traffic.
__global__ __launch_bounds__(1024)
void ntxent_one(const float* __restrict__ ts0, const float* __restrict__ rs0,
                const float* __restrict__ ts1, const float* __restrict__ rs1,
                const float* __restrict__ ts2, const float* __restrict__ rs2,
                float* __restrict__ out)
{
    __shared__ float red[16][528];   // per-wave: TT[256] | TR[256] | RRdiag[16]
    __shared__ float Gs[16][33];
    __shared__ float rn2[16], tnS[16], rnS[16];

    const int bid = blockIdx.x;
    const int b   = bid / 3;
    const int lvl = bid % 3;

    const float* tp; const float* rp; int D;
    if (lvl == 0)      { tp = ts0; rp = rs0; D = 4096; }
    else if (lvl == 1) { tp = ts1; rp = rs1; D = 2048; }
    else               { tp = ts2; rp = rs2; D = 1024; }

    const int t   = threadIdx.x;
    const int w   = t >> 6;          // wave 0..15
    const int l   = t & 63;
    const int row = l & 15;
    const int kg  = l >> 4;
    const int F   = D >> 4;          // floats per wave (256 / 128 / 64)

    const size_t base = (size_t)b * 16 * D + (size_t)row * D
                      + (size_t)w * F + (size_t)kg * 8;
    const float* tsrc = tp + base;
    const float* rsrc = rp + base;

    f32x4 acc_tt = {0.f, 0.f, 0.f, 0.f};
    f32x4 acc_tr = {0.f, 0.f, 0.f, 0.f};
    f32x4 acc_rr = {0.f, 0.f, 0.f, 0.f};

    if (lvl == 0) {                  // 8 K-steps, ring of 16-20 outstanding
        ISSUE(g0, 0) ISSUE(g1, 1) ISSUE(g2, 2) ISSUE(g3, 3)
        ISSUE(g4, 4) WAITVM(16); COMPUTE(g0)
        ISSUE(g5, 5) WAITVM(16); COMPUTE(g1)
        ISSUE(g6, 6) WAITVM(16); COMPUTE(g2)
        ISSUE(g7, 7) WAITVM(16); COMPUTE(g3)
        WAITVM(12);  COMPUTE(g4)
        WAITVM(8);   COMPUTE(g5)
        WAITVM(4);   COMPUTE(g6)
        WAITVM(0);   COMPUTE(g7)
    } else if (lvl == 1) {           // 4 K-steps, all 16 loads up front
        ISSUE(g0, 0) ISSUE(g1, 1) ISSUE(g2, 2) ISSUE(g3, 3)
        WAITVM(12);  COMPUTE(g0)
        WAITVM(8);   COMPUTE(g1)
        WAITVM(4);   COMPUTE(g2)
        WAITVM(0);   COMPUTE(g3)
    } else {                         // 2 K-steps
        ISSUE(g0, 0) ISSUE(g1, 1)
        WAITVM(4);   COMPUTE(g0)
        WAITVM(0);   COMPUTE(g1)
    }

    // ---- per-wave partials -> LDS ----
    const int m = row;
#pragma unroll
    for (int r = 0; r < 4; ++r) {
        const int n = kg * 4 + r;
        red[w][n * 16 + m]       = acc_tt[r];
        red[w][256 + n * 16 + m] = acc_tr[r];
    }
    if ((m >> 2) == kg) red[w][512 + m] = acc_rr[m & 3];
    __syncthreads();

    // ---- reduce 16 wave partials ----
    if (t < 256) {
        float stt = 0.f, str = 0.f;
#pragma unroll
        for (int p = 0; p < 16; ++p) {
            stt += red[p][t];
            str += red[p][256 + t];
        }
        Gs[t >> 4][t & 15]        = stt;
        Gs[t >> 4][16 + (t & 15)] = str;
    } else if (t < 272) {
        const int e = t - 256;
        float s = 0.f;
#pragma unroll
        for (int p = 0; p < 16; ++p) s += red[p][512 + e];
        rn2[e] = s;
    }
    __syncthreads();

    if (t < 16) {
        tnS[t] = fmaxf(sqrtf(Gs[t][t]), NTX_EPS);
        rnS[t] = fmaxf(sqrtf(rn2[t]), NTX_EPS);
    }
    __syncthreads();

    float loss = 0.f;
    if (t < 16) {
        const int n = t;
        const float itn = 2.0f / tnS[n];         // includes 1/temperature
        float lg[32];
#pragma unroll
        for (int j = 0; j < 16; ++j)
            lg[j] = Gs[n][16 + j] * itn / rnS[j];      // s_tr row
#pragma unroll
        for (int k = 0; k < 16; ++k)
            lg[16 + k] = Gs[n][k] * itn / tnS[k];      // s_tt row
        const float pos = lg[n];
        float mx = -3.4e38f;
#pragma unroll
        for (int j = 0; j < 32; ++j)
            mx = (j == 16 + n) ? mx : fmaxf(mx, lg[j]);    // exclude tt diag
        float sm = 0.f;
#pragma unroll
        for (int j = 0; j < 32; ++j)
            sm += (j == 16 + n) ? 0.f : expf(lg[j] - mx);
        loss = logf(sm) + mx - pos;
    }
    loss += __shfl_xor(loss, 1, 64);
    loss += __shfl_xor(loss, 2, 64);
    loss += __shfl_xor(loss, 4, 64);
    loss += __shfl_xor(loss, 8, 64);
    if (t == 0) atomicAdd(out, loss * (1.0f / 512.0f));
}

extern "C" void kernel_launch(void* const* d_in, const int* in_sizes, int n_in,
                              void* d_out, int out_size, void* d_ws, size_t ws_size,
                              hipStream_t stream) {
    const float* ts0 = (const float*)d_in[0];
    const float* rs0 = (const float*)d_in[1];
    const float* ts1 = (const float*)d_in[2];
    const float* rs1 = (const float*)d_in[3];
    const float* ts2 = (const float*)d_in[4];
    const float* rs2 = (const float*)d_in[5];
    float* out = (float*)d_out;

    hipMemsetAsync(out, 0, sizeof(float), stream);

    const int B = in_sizes[0] / (16 * 4096);   // 256
    hipLaunchKernelGGL(ntxent_one, dim3(B * 3), dim3(1024), 0, stream,
                       ts0, rs0, ts1, rs1, ts2, rs2, out);
}

// Round 16
// 52.269 us; speedup vs baseline: 9.5234x; 1.1287x over previous
//
#include <hip/hip_runtime.h>
#include <math.h>

#define NTX_EPS 1e-8f

typedef __fp16 half8 __attribute__((ext_vector_type(8)));
typedef __fp16 half2v __attribute__((ext_vector_type(2)));
typedef float f32x4 __attribute__((ext_vector_type(4)));

union H8 { half8 v8; half2v v2[4]; };

__device__ __forceinline__ half8 pack8(const float4& a, const float4& b) {
    H8 u;
    u.v2[0] = __builtin_amdgcn_cvt_pkrtz(a.x, a.y);
    u.v2[1] = __builtin_amdgcn_cvt_pkrtz(a.z, a.w);
    u.v2[2] = __builtin_amdgcn_cvt_pkrtz(b.x, b.y);
    u.v2[3] = __builtin_amdgcn_cvt_pkrtz(b.z, b.w);
    return u.v8;
}

// Opaque async load (R12-proven): one global_load_dwordx4 per call; compiler
// cannot recycle destinations into a serialized chain.
__device__ __forceinline__ float4 gl4(const float* p) {
    float4 d;
    asm volatile("global_load_dwordx4 %0, %1, off" : "=v"(d) : "v"(p) : "memory");
    return d;
}
#define WAITVM(n) do { asm volatile("s_waitcnt vmcnt(" #n ")" ::: "memory"); \
                       __builtin_amdgcn_sched_barrier(0); } while (0)

#define ISSUE(g, s) \
    float4 g##T0 = gl4(tsrc + (s) * 32); \
    float4 g##T1 = gl4(tsrc + (s) * 32 + 4); \
    float4 g##R0 = gl4(rsrc + (s) * 32); \
    float4 g##R1 = gl4(rsrc + (s) * 32 + 4);

#define COMPUTE(g) { \
    half8 tf = pack8(g##T0, g##T1); \
    half8 rf = pack8(g##R0, g##R1); \
    acc_tt = __builtin_amdgcn_mfma_f32_16x16x32_f16(tf, tf, acc_tt, 0, 0, 0); \
    acc_tr = __builtin_amdgcn_mfma_f32_16x16x32_f16(tf, rf, acc_tr, 0, 0, 0); \
    acc_rr = __builtin_amdgcn_mfma_f32_16x16x32_f16(rf, rf, acc_rr, 0, 0, 0); }

// Reduce 16 wave-partial Grams in LDS and compute one level's loss.
// Returns the loss (valid at t==0 only). Safe to call twice back-to-back:
// each call's first barrier separates its red-writes from the previous
// call's red-reads.
__device__ __forceinline__ float reduce_loss(
    float (*red)[528], float (*Gs)[33], float* rn2, float* tnS, float* rnS,
    int t, int w, int row, int kg,
    const f32x4& acc_tt, const f32x4& acc_tr, const f32x4& acc_rr)
{
    const int m = row;
#pragma unroll
    for (int r = 0; r < 4; ++r) {
        const int n = kg * 4 + r;
        red[w][n * 16 + m]       = acc_tt[r];
        red[w][256 + n * 16 + m] = acc_tr[r];
    }
    if ((m >> 2) == kg) red[w][512 + m] = acc_rr[m & 3];
    __syncthreads();

    if (t < 256) {
        float stt = 0.f, str = 0.f;
#pragma unroll
        for (int p = 0; p < 16; ++p) {
            stt += red[p][t];
            str += red[p][256 + t];
        }
        Gs[t >> 4][t & 15]        = stt;
        Gs[t >> 4][16 + (t & 15)] = str;
    } else if (t < 272) {
        const int e = t - 256;
        float s = 0.f;
#pragma unroll
        for (int p = 0; p < 16; ++p) s += red[p][512 + e];
        rn2[e] = s;
    }
    __syncthreads();

    if (t < 16) {
        tnS[t] = fmaxf(sqrtf(Gs[t][t]), NTX_EPS);
        rnS[t] = fmaxf(sqrtf(rn2[t]), NTX_EPS);
    }
    __syncthreads();

    float loss = 0.f;
    if (t < 16) {
        const int n = t;
        const float itn = 2.0f / tnS[n];         // includes 1/temperature
        float lg[32];
#pragma unroll
        for (int j = 0; j < 16; ++j)
            lg[j] = Gs[n][16 + j] * itn / rnS[j];      // s_tr row
#pragma unroll
        for (int k = 0; k < 16; ++k)
            lg[16 + k] = Gs[n][k] * itn / tnS[k];      // s_tt row
        const float pos = lg[n];
        float mx = -3.4e38f;
#pragma unroll
        for (int j = 0; j < 32; ++j)
            mx = (j == 16 + n) ? mx : fmaxf(mx, lg[j]);    // exclude tt diag
        float sm = 0.f;
#pragma unroll
        for (int j = 0; j < 32; ++j)
            sm += (j == 16 + n) ? 0.f : expf(lg[j] - mx);
        loss = logf(sm) + mx - pos;
    }
    loss += __shfl_xor(loss, 1, 64);
    loss += __shfl_xor(loss, 2, 64);
    loss += __shfl_xor(loss, 4, 64);
    loss += __shfl_xor(loss, 8, 64);
    return loss;                                  // valid at t==0
}

// SINGLE kernel: 512 blocks x 1024 threads (16 waves) = EXACTLY 2 blocks/CU
// (32-wave cap), zero queued-block tail. Block (b = bid>>1, type = bid&1):
//   type 0: level 0 of batch b        (512 KB streamed)
//   type 1: level 1 THEN level 2 of b (256 + 128 KB, sequential)
// Per-CU totals balance exactly (one of each type = 875 KB). Each wave runs
// the verified R12 ISA load-ring on its own d-sub-range (lane l feeds Gram
// row l&15, k-group l>>4; one half8 is both A and B; mfma(t,t)/(t,r)/(r,r);
// C/D col=l&15, row=kg*4+r). In-block 16-wave LDS reduce + loss; one
// atomicAdd per block. No fences (R14 lesson), no ws, no extra kernels.
// VGPR must stay <=64 for 8 waves/SIMD (R15 build: 52).
__global__ __launch_bounds__(1024)
void ntxent_one(const float* __restrict__ ts0, const float* __restrict__ rs0,
                const float* __restrict__ ts1, const float* __restrict__ rs1,
                const float* __restrict__ ts2, const float* __restrict__ rs2,
                float* __restrict__ out)
{
    __shared__ float red[16][528];
    __shared__ float Gs[16][33];
    __shared__ float rn2[16], tnS[16], rnS[16];

    const int bid  = blockIdx.x;
    const int b    = bid >> 1;
    const int type = bid & 1;

    const int t   = threadIdx.x;
    const int w   = t >> 6;          // wave 0..15
    const int l   = t & 63;
    const int row = l & 15;
    const int kg  = l >> 4;

    float lossTot = 0.f;             // valid at t==0

    if (type == 0) {
        // ---- level 0: D=4096, 256 floats/wave, 8 K-steps, depth-20 ring ----
        const int D = 4096;
        const size_t base = (size_t)b * 16 * D + (size_t)row * D
                          + (size_t)w * 256 + (size_t)kg * 8;
        const float* tsrc = ts0 + base;
        const float* rsrc = rs0 + base;
        f32x4 acc_tt = {0.f, 0.f, 0.f, 0.f};
        f32x4 acc_tr = {0.f, 0.f, 0.f, 0.f};
        f32x4 acc_rr = {0.f, 0.f, 0.f, 0.f};
        ISSUE(g0, 0) ISSUE(g1, 1) ISSUE(g2, 2) ISSUE(g3, 3)
        ISSUE(g4, 4) WAITVM(16); COMPUTE(g0)
        ISSUE(g5, 5) WAITVM(16); COMPUTE(g1)
        ISSUE(g6, 6) WAITVM(16); COMPUTE(g2)
        ISSUE(g7, 7) WAITVM(16); COMPUTE(g3)
        WAITVM(12);  COMPUTE(g4)
        WAITVM(8);   COMPUTE(g5)
        WAITVM(4);   COMPUTE(g6)
        WAITVM(0);   COMPUTE(g7)
        lossTot = reduce_loss(red, Gs, rn2, tnS, rnS, t, w, row, kg,
                              acc_tt, acc_tr, acc_rr);
    } else {
        // ---- level 1: D=2048, 128 floats/wave, 4 K-steps ----
        {
            const int D = 2048;
            const size_t base = (size_t)b * 16 * D + (size_t)row * D
                              + (size_t)w * 128 + (size_t)kg * 8;
            const float* tsrc = ts1 + base;
            const float* rsrc = rs1 + base;
            f32x4 acc_tt = {0.f, 0.f, 0.f, 0.f};
            f32x4 acc_tr = {0.f, 0.f, 0.f, 0.f};
            f32x4 acc_rr = {0.f, 0.f, 0.f, 0.f};
            ISSUE(g0, 0) ISSUE(g1, 1) ISSUE(g2, 2) ISSUE(g3, 3)
            WAITVM(12);  COMPUTE(g0)
            WAITVM(8);   COMPUTE(g1)
            WAITVM(4);   COMPUTE(g2)
            WAITVM(0);   COMPUTE(g3)
            lossTot = reduce_loss(red, Gs, rn2, tnS, rnS, t, w, row, kg,
                                  acc_tt, acc_tr, acc_rr);
        }
        // ---- level 2: D=1024, 64 floats/wave, 2 K-steps ----
        {
            const int D = 1024;
            const size_t base = (size_t)b * 16 * D + (size_t)row * D
                              + (size_t)w * 64 + (size_t)kg * 8;
            const float* tsrc = ts2 + base;
            const float* rsrc = rs2 + base;
            f32x4 acc_tt = {0.f, 0.f, 0.f, 0.f};
            f32x4 acc_tr = {0.f, 0.f, 0.f, 0.f};
            f32x4 acc_rr = {0.f, 0.f, 0.f, 0.f};
            ISSUE(g0, 0) ISSUE(g1, 1)
            WAITVM(4);   COMPUTE(g0)
            WAITVM(0);   COMPUTE(g1)
            lossTot += reduce_loss(red, Gs, rn2, tnS, rnS, t, w, row, kg,
                                   acc_tt, acc_tr, acc_rr);
        }
    }

    if (t == 0) atomicAdd(out, lossTot * (1.0f / 512.0f));
}

extern "C" void kernel_launch(void* const* d_in, const int* in_sizes, int n_in,
                              void* d_out, int out_size, void* d_ws, size_t ws_size,
                              hipStream_t stream) {
    const float* ts0 = (const float*)d_in[0];
    const float* rs0 = (const float*)d_in[1];
    const float* ts1 = (const float*)d_in[2];
    const float* rs1 = (const float*)d_in[3];
    const float* ts2 = (const float*)d_in[4];
    const float* rs2 = (const float*)d_in[5];
    float* out = (float*)d_out;

    hipMemsetAsync(out, 0, sizeof(float), stream);

    const int B = in_sizes[0] / (16 * 4096);   // 256
    hipLaunchKernelGGL(ntxent_one, dim3(B * 2), dim3(1024), 0, stream,
                       ts0, rs0, ts1, rs1, ts2, rs2, out);
}